// Round 4
// baseline (120.232 us; speedup 1.0000x reference)
//
#include <hip/hip_runtime.h>

// Problem: inputs [8192, 8192] f32. Semantics: idx = nonzero(x); out = idx.sum(0) -> int64 [2]
//   out[0] = sum of row-index i over nonzeros; out[1] = sum of col-index j over nonzeros.
// Harness reads d_out as int32 (int64 ref wrapped via astype(np.int32)) -> write low 32 bits.

#define DIM1 8192u
#define NBLK 2048u
#define NTHR (NBLK * 256u)          // 524288 threads; 32 float4s each, exact cover
#define N4   (8192u * 8192u / 4u)   // 16777216 float4s

typedef unsigned long long u64;

__device__ __forceinline__ void nz_accum(float4 v, unsigned q,
                                         unsigned& si, unsigned& sj) {
    unsigned i  = q >> 11;                // row index: q / (8192/4)
    unsigned jb = (q << 2) & (DIM1 - 1u); // col index of v.x
    if (v.x != 0.0f) { si += i; sj += jb;      }
    if (v.y != 0.0f) { si += i; sj += jb + 1u; }
    if (v.z != 0.0f) { si += i; sj += jb + 2u; }
    if (v.w != 0.0f) { si += i; sj += jb + 3u; }
}

// launch_bounds(256, 8): 8 blocks/CU -> 32 waves/CU, caps VGPR at 64 so the
// 8-deep load pipeline (32 data VGPRs) can't blow occupancy.
__global__ __launch_bounds__(256, 8) void nz_idx_sum_kernel(
    const float4* __restrict__ in, u64* __restrict__ ws, int* __restrict__ out) {
    const unsigned tid = blockIdx.x * 256u + threadIdx.x;
    unsigned si = 0u, sj = 0u;  // per-thread partials fit u32 (max ~1.05e6)

#pragma unroll 1                 // keep the 4-iter loop rolled: 8 loads in flight, ~50 VGPRs
    for (unsigned g = 0u; g < 4u; ++g) {
        const unsigned qb = tid + g * (8u * NTHR);
        float4 v0 = in[qb];
        float4 v1 = in[qb + 1u * NTHR];
        float4 v2 = in[qb + 2u * NTHR];
        float4 v3 = in[qb + 3u * NTHR];
        float4 v4 = in[qb + 4u * NTHR];
        float4 v5 = in[qb + 5u * NTHR];
        float4 v6 = in[qb + 6u * NTHR];
        float4 v7 = in[qb + 7u * NTHR];
        nz_accum(v0, qb,             si, sj);
        nz_accum(v1, qb + 1u * NTHR, si, sj);
        nz_accum(v2, qb + 2u * NTHR, si, sj);
        nz_accum(v3, qb + 3u * NTHR, si, sj);
        nz_accum(v4, qb + 4u * NTHR, si, sj);
        nz_accum(v5, qb + 5u * NTHR, si, sj);
        nz_accum(v6, qb + 6u * NTHR, si, sj);
        nz_accum(v7, qb + 7u * NTHR, si, sj);
    }

    // wave64 reduce (u32; wave partial max ~6.7e7, fits)
    for (int off = 32; off > 0; off >>= 1) {
        si += __shfl_down(si, off, 64);
        sj += __shfl_down(sj, off, 64);
    }

    __shared__ unsigned s_i[4], s_j[4];
    const int wave = threadIdx.x >> 6;
    const int lane = threadIdx.x & 63;
    if (lane == 0) { s_i[wave] = si; s_j[wave] = sj; }
    __syncthreads();

    if (threadIdx.x == 0) {
        u64 ti = 0, tj = 0;
        for (int w = 0; w < 4; ++w) { ti += (u64)s_i[w]; tj += (u64)s_j[w]; }
        atomicAdd(&ws[0], ti);  // device-scope: safe across XCDs
        atomicAdd(&ws[1], tj);
        __threadfence();        // order my adds before the done-counter bump
        unsigned done = atomicAdd((unsigned*)(ws + 2), 1u);
        if (done == NBLK - 1u) {
            // last block: all partials are in (each block fenced before bumping)
            u64 a = atomicAdd(&ws[0], 0ull);  // atomic read at coherence point
            u64 b = atomicAdd(&ws[1], 0ull);
            out[0] = (int)(unsigned)(a & 0xFFFFFFFFull);  // int64 -> int32 wrap
            out[1] = (int)(unsigned)(b & 0xFFFFFFFFull);
        }
    }
}

extern "C" void kernel_launch(void* const* d_in, const int* in_sizes, int n_in,
                              void* d_out, int out_size, void* d_ws, size_t ws_size,
                              hipStream_t stream) {
    const float4* in = (const float4*)d_in[0];
    u64* ws = (u64*)d_ws;
    int* out = (int*)d_out;

    // zero accumulators + done-counter every call (capture-safe, deterministic;
    // cannot self-reset in-kernel: d_ws is poisoned 0xAA after the correctness call)
    hipMemsetAsync(d_ws, 0, 3 * sizeof(u64), stream);

    nz_idx_sum_kernel<<<NBLK, 256, 0, stream>>>(in, ws, out);
}